// Round 2
// baseline (3026.614 us; speedup 1.0000x reference)
//
#include <hip/hip_runtime.h>

#define NN 4096
#define NSTEPS 100
#define TPB 512
#define NBLK 256   // 1 block per CU; 16 rows per block, K in VGPRs

__device__ __forceinline__ float wave_sum64(float v) {
#pragma unroll
    for (int off = 32; off; off >>= 1) v += __shfl_xor(v, off, 64);
    return v;
}

// Flag/generation grid barrier. flags[256], gen — zeroed by hipMemsetAsync
// before launch; targets are monotonically increasing so no reset needed.
__device__ __forceinline__ void grid_sync(int* flags, int* gen, int target) {
    __syncthreads();
    if (threadIdx.x == 0) {
        __threadfence();  // make this block's z writes device-visible
        __hip_atomic_store(&flags[blockIdx.x], target, __ATOMIC_RELEASE,
                           __HIP_MEMORY_SCOPE_AGENT);
    }
    if (blockIdx.x == 0) {
        if (threadIdx.x < 64) {
            const int i0 = threadIdx.x * 4;  // each lane watches 4 blocks
            for (;;) {
                int a0 = __hip_atomic_load(&flags[i0 + 0], __ATOMIC_ACQUIRE, __HIP_MEMORY_SCOPE_AGENT);
                int a1 = __hip_atomic_load(&flags[i0 + 1], __ATOMIC_ACQUIRE, __HIP_MEMORY_SCOPE_AGENT);
                int a2 = __hip_atomic_load(&flags[i0 + 2], __ATOMIC_ACQUIRE, __HIP_MEMORY_SCOPE_AGENT);
                int a3 = __hip_atomic_load(&flags[i0 + 3], __ATOMIC_ACQUIRE, __HIP_MEMORY_SCOPE_AGENT);
                int m = min(min(a0, a1), min(a2, a3));
                if (__all(m >= target)) break;
                __builtin_amdgcn_s_sleep(1);
            }
            if (threadIdx.x == 0) {
                __threadfence();
                __hip_atomic_store(gen, target, __ATOMIC_RELEASE, __HIP_MEMORY_SCOPE_AGENT);
            }
        }
    } else {
        if (threadIdx.x == 0) {
            while (__hip_atomic_load(gen, __ATOMIC_ACQUIRE, __HIP_MEMORY_SCOPE_AGENT) < target)
                __builtin_amdgcn_s_sleep(1);
        }
    }
    __syncthreads();
}

// Persistent kernel: K resident in VGPRs, z staged to LDS each step.
// Block b owns rows [16b, 16b+16). Wave w: row-group g=w>>1 (4 rows),
// col-half h=w&1 (2048 cols). Lane l, chunk j: cols h*2048 + j*256 + 4l..+3.
__global__ __launch_bounds__(TPB, 2) void k_persist(
    const float* __restrict__ K, const float2* __restrict__ z0,
    float2* __restrict__ zb0, float2* __restrict__ zb1,
    float2* __restrict__ zfinal, const float* __restrict__ omega_p,
    const float* __restrict__ dt_p, int* flags, int* gen) {
    __shared__ float zr[NN];
    __shared__ float zi[NN];
    __shared__ float P[8][8];

    const int tid  = threadIdx.x;
    const int bid  = blockIdx.x;
    const int w    = tid >> 6, lane = tid & 63;
    const int g    = w >> 1,   h    = w & 1;
    const int rb   = bid * 16 + g * 4;          // first of this wave's 4 rows
    const int cb   = h * 2048 + lane * 4;       // lane's col base (j stride 256)

    const float omega = *omega_p;
    const float dt    = *dt_p;
    const float inv2n = 1.0f / (2.0f * NN);

    // ---- load K fragment into registers: 4 rows x 8 float4 = 128 VGPRs ----
    float4 kA[4][8];
#pragma unroll
    for (int r = 0; r < 4; ++r) {
        const float* Kr = K + (size_t)(rb + r) * NN + cb;
#pragma unroll
        for (int j = 0; j < 8; ++j) kA[r][j] = *(const float4*)(Kr + j * 256);
    }

    const float2* zin = z0;
    for (int s = 0; s < NSTEPS; ++s) {
        // ---- stage z -> LDS (SoA) ----
        const float4* z4 = (const float4*)zin;   // 2 complex per float4
#pragma unroll
        for (int it = 0; it < 4; ++it) {
            int idx = it * TPB + tid;            // 0..2047
            float4 v = z4[idx];
            zr[2 * idx]     = v.x;  zi[2 * idx]     = v.y;
            zr[2 * idx + 1] = v.z;  zi[2 * idx + 1] = v.w;
        }
        __syncthreads();

        // ---- dot products: 4 rows x 2048 cols per wave ----
        float sr0 = 0, sr1 = 0, sr2 = 0, sr3 = 0;
        float si0 = 0, si1 = 0, si2 = 0, si3 = 0;
#pragma unroll
        for (int j = 0; j < 8; ++j) {
            float4 a = *(const float4*)&zr[cb + j * 256];
            float4 b = *(const float4*)&zi[cb + j * 256];
            float4 k0 = kA[0][j], k1 = kA[1][j], k2 = kA[2][j], k3 = kA[3][j];
            sr0 += k0.x * a.x + k0.y * a.y + k0.z * a.z + k0.w * a.w;
            si0 += k0.x * b.x + k0.y * b.y + k0.z * b.z + k0.w * b.w;
            sr1 += k1.x * a.x + k1.y * a.y + k1.z * a.z + k1.w * a.w;
            si1 += k1.x * b.x + k1.y * b.y + k1.z * b.z + k1.w * b.w;
            sr2 += k2.x * a.x + k2.y * a.y + k2.z * a.z + k2.w * a.w;
            si2 += k2.x * b.x + k2.y * b.y + k2.z * b.z + k2.w * b.w;
            sr3 += k3.x * a.x + k3.y * a.y + k3.z * a.z + k3.w * a.w;
            si3 += k3.x * b.x + k3.y * b.y + k3.z * b.z + k3.w * b.w;
        }
        sr0 = wave_sum64(sr0); si0 = wave_sum64(si0);
        sr1 = wave_sum64(sr1); si1 = wave_sum64(si1);
        sr2 = wave_sum64(sr2); si2 = wave_sum64(si2);
        sr3 = wave_sum64(sr3); si3 = wave_sum64(si3);
        if (lane == 0) {
            P[w][0] = sr0; P[w][1] = sr1; P[w][2] = sr2; P[w][3] = sr3;
            P[w][4] = si0; P[w][5] = si1; P[w][6] = si2; P[w][7] = si3;
        }
        __syncthreads();

        // ---- per-row ODE update (threads 0..15) ----
        float2* zo = (s == NSTEPS - 1) ? zfinal : ((s & 1) ? zb1 : zb0);
        if (tid < 16) {
            int g2 = tid >> 2, i = tid & 3;
            float u = P[2 * g2][i]     + P[2 * g2 + 1][i];      // Re(K z)
            float v = P[2 * g2][4 + i] + P[2 * g2 + 1][4 + i];  // Im(K z)
            int gr = bid * 16 + tid;
            float x = zr[gr], y = zi[gr];
            float A = x * x - y * y;           // Re(z^2)
            float B = 2.0f * x * y;            // Im(z^2)
            float dzr = inv2n * (u - (u * A + v * B)) + omega * x;
            float dzi = inv2n * (v - (u * B - v * A)) + omega * y;
            float nx = x + dt * dzr;
            float ny = y + dt * dzi;
            float a2 = nx * nx + ny * ny;
            if (a2 >= 0.999f * 0.999f) {
                float sc = 0.999f / sqrtf(a2);
                nx *= sc; ny *= sc;
            }
            zo[gr] = make_float2(nx, ny);
        }
        if (s != NSTEPS - 1) grid_sync(flags, gen, s + 1);
        zin = zo;
    }
}

// ---- generic fallback (n != 4096 or tiny workspace): per-step launches ----
__global__ __launch_bounds__(256) void k_step_f32(
    const float* __restrict__ K, const float2* __restrict__ zin,
    float2* __restrict__ zout, const float* __restrict__ omega_p,
    const float* __restrict__ dt_p, int n) {
    const int wave = threadIdx.x >> 6;
    const int lane = threadIdx.x & 63;
    const int row  = blockIdx.x * 4 + wave;
    if (row >= n) return;
    const float2* z2 = zin;
    float sr = 0.0f, si = 0.0f;
    for (int c = lane; c < n; c += 64) {
        float k = K[(size_t)row * n + c];
        float2 z = z2[c];
        sr += k * z.x;
        si += k * z.y;
    }
#pragma unroll
    for (int off = 32; off; off >>= 1) {
        sr += __shfl_down(sr, off, 64);
        si += __shfl_down(si, off, 64);
    }
    if (lane == 0) {
        float u = sr, v = si;
        float2 zc = zin[row];
        float x = zc.x, y = zc.y;
        float inv2n = 1.0f / (2.0f * n);
        float A = x * x - y * y, B = 2.0f * x * y;
        float dzr = inv2n * (u - (u * A + v * B)) + (*omega_p) * x;
        float dzi = inv2n * (v - (u * B - v * A)) + (*omega_p) * y;
        float nx = x + (*dt_p) * dzr, ny = y + (*dt_p) * dzi;
        float a2 = nx * nx + ny * ny;
        if (a2 >= 0.999f * 0.999f) { float sc = 0.999f / sqrtf(a2); nx *= sc; ny *= sc; }
        zout[row] = make_float2(nx, ny);
    }
}

extern "C" void kernel_launch(void* const* d_in, const int* in_sizes, int n_in,
                              void* d_out, int out_size, void* d_ws, size_t ws_size,
                              hipStream_t stream) {
    const float2* z0      = (const float2*)d_in[0];
    const float*  K       = (const float*)d_in[1];
    const float*  omega_p = (const float*)d_in[2];
    const float*  dt_p    = (const float*)d_in[3];
    const int n = in_sizes[0] / 2;
    float2* out = (float2*)d_out;

    const size_t need = 4096 + 2 * (size_t)NN * sizeof(float2);
    if (n == NN && ws_size >= need) {
        int*    flags = (int*)d_ws;
        int*    gen   = (int*)d_ws + 256;
        float2* zb0   = (float2*)((char*)d_ws + 4096);
        float2* zb1   = zb0 + NN;
        hipMemsetAsync(d_ws, 0, 2048, stream);  // flags + gen = 0
        k_persist<<<NBLK, TPB, 0, stream>>>(K, z0, zb0, zb1, out,
                                            omega_p, dt_p, flags, gen);
    } else {
        float2* zb0 = (float2*)d_ws;
        float2* zb1 = zb0 + n;
        const float2* cur = z0;
        for (int s = 0; s < NSTEPS; ++s) {
            float2* nxt = (s == NSTEPS - 1) ? out : ((s & 1) ? zb1 : zb0);
            k_step_f32<<<(n + 3) / 4, 256, 0, stream>>>(K, cur, nxt, omega_p, dt_p, n);
            cur = nxt;
        }
    }
}

// Round 3
// 760.479 us; speedup vs baseline: 3.9799x; 3.9799x over previous
//
#include <hip/hip_runtime.h>

#define NN 4096
#define NSTEPS 100
#define TPB 512
#define NBLK 256     // 1 block per CU; 16 rows per block, K pinned in VGPRs
#define FSTRIDE 16   // flags padded to 64B to spread cache lines

// Coherent (cross-XCD) 8-byte load/store: relaxed agent-scope atomics compile
// to sc-flagged global ops that bypass the non-coherent L1/L2 and hit the
// coherence point directly — crucially WITHOUT the buffer_wbl2 / buffer_inv
// cache maintenance that release/acquire fences emit (the R1 killer).
__device__ __forceinline__ void zstore(float2* p, float2 v) {
    union { float2 f; unsigned long long u; } c; c.f = v;
    __hip_atomic_store((unsigned long long*)p, c.u, __ATOMIC_RELAXED,
                       __HIP_MEMORY_SCOPE_AGENT);
}
__device__ __forceinline__ float2 zload(const float2* p) {
    unsigned long long u = __hip_atomic_load((const unsigned long long*)p,
                                             __ATOMIC_RELAXED,
                                             __HIP_MEMORY_SCOPE_AGENT);
    union { unsigned long long u; float2 f; } c; c.u = u;
    return c.f;
}

// Persistent kernel: K in VGPRs (asm-pinned), z staged to LDS each step,
// flag barrier with relaxed agent atomics only.
__global__ __launch_bounds__(TPB, 2) void k_persist(
    const float* __restrict__ K, const float2* __restrict__ z0,
    float2* __restrict__ zb0, float2* __restrict__ zb1,
    float2* __restrict__ zfinal, const float* __restrict__ omega_p,
    const float* __restrict__ dt_p, int* flags) {
    __shared__ float zr[NN];
    __shared__ float zi[NN];
    __shared__ float P[8][8];
    __shared__ int lbar;

    const int tid  = threadIdx.x;
    const int bid  = blockIdx.x;
    const int w    = tid >> 6, lane = tid & 63;
    const int g    = w >> 1,   h    = w & 1;
    const int rb   = bid * 16 + g * 4;          // first of this wave's 4 rows
    const int cb   = h * 2048 + lane * 4;       // lane's col base (j stride 256)

    const float omega = *omega_p;
    const float dt    = *dt_p;
    const float inv2n = 1.0f / (2.0f * NN);

    if (tid == 0) lbar = 0;

    // ---- load K fragment: 4 rows x 8 float4 = 128 VGPRs ----
    float4 kA[4][8];
#pragma unroll
    for (int r = 0; r < 4; ++r) {
        const float* Kr = K + (size_t)(rb + r) * NN + cb;
#pragma unroll
        for (int j = 0; j < 8; ++j) kA[r][j] = *(const float4*)(Kr + j * 256);
    }

    const float2* zin = z0;
    for (int s = 0; s < NSTEPS; ++s) {
        // Pin kA in registers: opaque redefinition each iteration so the
        // compiler can neither spill-and-reload nor refold the global loads.
#pragma unroll
        for (int r = 0; r < 4; ++r)
#pragma unroll
            for (int j = 0; j < 8; ++j)
                asm volatile("" : "+v"(kA[r][j].x), "+v"(kA[r][j].y),
                                  "+v"(kA[r][j].z), "+v"(kA[r][j].w));

        // ---- stage z -> LDS (SoA), coherent loads ----
#pragma unroll
        for (int it = 0; it < 8; ++it) {
            int idx = it * TPB + tid;            // 0..4095
            float2 v = zload(zin + idx);
            zr[idx] = v.x; zi[idx] = v.y;
        }
        __syncthreads();

        // ---- dots: 4 rows x 2048 cols per wave, K from regs, z from LDS ----
        float sr0 = 0, sr1 = 0, sr2 = 0, sr3 = 0;
        float si0 = 0, si1 = 0, si2 = 0, si3 = 0;
#pragma unroll
        for (int j = 0; j < 8; ++j) {
            float4 a = *(const float4*)&zr[cb + j * 256];
            float4 b = *(const float4*)&zi[cb + j * 256];
            float4 k0 = kA[0][j], k1 = kA[1][j], k2 = kA[2][j], k3 = kA[3][j];
            sr0 += k0.x * a.x + k0.y * a.y + k0.z * a.z + k0.w * a.w;
            si0 += k0.x * b.x + k0.y * b.y + k0.z * b.z + k0.w * b.w;
            sr1 += k1.x * a.x + k1.y * a.y + k1.z * a.z + k1.w * a.w;
            si1 += k1.x * b.x + k1.y * b.y + k1.z * b.z + k1.w * b.w;
            sr2 += k2.x * a.x + k2.y * a.y + k2.z * a.z + k2.w * a.w;
            si2 += k2.x * b.x + k2.y * b.y + k2.z * b.z + k2.w * b.w;
            sr3 += k3.x * a.x + k3.y * a.y + k3.z * a.z + k3.w * a.w;
            si3 += k3.x * b.x + k3.y * b.y + k3.z * b.z + k3.w * b.w;
        }
#pragma unroll
        for (int off = 32; off; off >>= 1) {
            sr0 += __shfl_xor(sr0, off, 64); si0 += __shfl_xor(si0, off, 64);
            sr1 += __shfl_xor(sr1, off, 64); si1 += __shfl_xor(si1, off, 64);
            sr2 += __shfl_xor(sr2, off, 64); si2 += __shfl_xor(si2, off, 64);
            sr3 += __shfl_xor(sr3, off, 64); si3 += __shfl_xor(si3, off, 64);
        }
        if (lane == 0) {
            P[w][0] = sr0; P[w][1] = sr1; P[w][2] = sr2; P[w][3] = sr3;
            P[w][4] = si0; P[w][5] = si1; P[w][6] = si2; P[w][7] = si3;
        }
        __syncthreads();

        // ---- per-row ODE update (wave 0, threads 0..15) ----
        float2* zo = (s == NSTEPS - 1) ? zfinal : ((s & 1) ? zb1 : zb0);
        if (tid < 16) {
            int g2 = tid >> 2, i = tid & 3;
            float u = P[2 * g2][i]     + P[2 * g2 + 1][i];      // Re(K z)
            float v = P[2 * g2][4 + i] + P[2 * g2 + 1][4 + i];  // Im(K z)
            int gr = bid * 16 + tid;
            float x = zr[gr], y = zi[gr];
            float A = x * x - y * y;           // Re(z^2)
            float B = 2.0f * x * y;            // Im(z^2)
            float dzr = inv2n * (u - (u * A + v * B)) + omega * x;
            float dzi = inv2n * (v - (u * B - v * A)) + omega * y;
            float nx = x + dt * dzr;
            float ny = y + dt * dzi;
            float a2 = nx * nx + ny * ny;
            if (a2 >= 0.999f * 0.999f) {
                float sc = 0.999f / sqrtf(a2);
                nx *= sc; ny *= sc;
            }
            zstore(zo + gr, make_float2(nx, ny));
        }

        // ---- barrier (skip after last step) ----
        if (s != NSTEPS - 1) {
            const int target = s + 1;
            if (w == 0) {
                __builtin_amdgcn_s_waitcnt(0);   // z stores ack'd at coherence pt
                __atomic_signal_fence(__ATOMIC_SEQ_CST);
                if (tid == 0)
                    __hip_atomic_store(&flags[bid * FSTRIDE], target,
                                       __ATOMIC_RELAXED, __HIP_MEMORY_SCOPE_AGENT);
                const int i0 = lane * 4;
                for (;;) {
                    int a0 = __hip_atomic_load(&flags[(i0 + 0) * FSTRIDE], __ATOMIC_RELAXED, __HIP_MEMORY_SCOPE_AGENT);
                    int a1 = __hip_atomic_load(&flags[(i0 + 1) * FSTRIDE], __ATOMIC_RELAXED, __HIP_MEMORY_SCOPE_AGENT);
                    int a2 = __hip_atomic_load(&flags[(i0 + 2) * FSTRIDE], __ATOMIC_RELAXED, __HIP_MEMORY_SCOPE_AGENT);
                    int a3 = __hip_atomic_load(&flags[(i0 + 3) * FSTRIDE], __ATOMIC_RELAXED, __HIP_MEMORY_SCOPE_AGENT);
                    int m = min(min(a0, a1), min(a2, a3));
                    if (__all(m >= target)) break;
                    __builtin_amdgcn_s_sleep(1);
                }
                __atomic_signal_fence(__ATOMIC_SEQ_CST);
                if (lane == 0) *(volatile int*)&lbar = target;
            } else {
                while (*(volatile int*)&lbar < target) __builtin_amdgcn_s_sleep(1);
                __atomic_signal_fence(__ATOMIC_SEQ_CST);
            }
        }
        zin = zo;
    }
}

// ---- generic fallback: per-step launches ----
__global__ __launch_bounds__(256) void k_step_f32(
    const float* __restrict__ K, const float2* __restrict__ zin,
    float2* __restrict__ zout, const float* __restrict__ omega_p,
    const float* __restrict__ dt_p, int n) {
    const int wave = threadIdx.x >> 6;
    const int lane = threadIdx.x & 63;
    const int row  = blockIdx.x * 4 + wave;
    if (row >= n) return;
    float sr = 0.0f, si = 0.0f;
    for (int c = lane; c < n; c += 64) {
        float k = K[(size_t)row * n + c];
        float2 z = zin[c];
        sr += k * z.x;
        si += k * z.y;
    }
#pragma unroll
    for (int off = 32; off; off >>= 1) {
        sr += __shfl_down(sr, off, 64);
        si += __shfl_down(si, off, 64);
    }
    if (lane == 0) {
        float u = sr, v = si;
        float2 zc = zin[row];
        float x = zc.x, y = zc.y;
        float inv2n = 1.0f / (2.0f * n);
        float A = x * x - y * y, B = 2.0f * x * y;
        float dzr = inv2n * (u - (u * A + v * B)) + (*omega_p) * x;
        float dzi = inv2n * (v - (u * B - v * A)) + (*omega_p) * y;
        float nx = x + (*dt_p) * dzr, ny = y + (*dt_p) * dzi;
        float a2 = nx * nx + ny * ny;
        if (a2 >= 0.999f * 0.999f) { float sc = 0.999f / sqrtf(a2); nx *= sc; ny *= sc; }
        zout[row] = make_float2(nx, ny);
    }
}

extern "C" void kernel_launch(void* const* d_in, const int* in_sizes, int n_in,
                              void* d_out, int out_size, void* d_ws, size_t ws_size,
                              hipStream_t stream) {
    const float2* z0      = (const float2*)d_in[0];
    const float*  K       = (const float*)d_in[1];
    const float*  omega_p = (const float*)d_in[2];
    const float*  dt_p    = (const float*)d_in[3];
    const int n = in_sizes[0] / 2;
    float2* out = (float2*)d_out;

    const size_t flags_bytes = NBLK * FSTRIDE * sizeof(int);  // 16 KB
    const size_t need = flags_bytes + 2 * (size_t)NN * sizeof(float2);
    if (n == NN && ws_size >= need) {
        int*    flags = (int*)d_ws;
        float2* zb0   = (float2*)((char*)d_ws + flags_bytes);
        float2* zb1   = zb0 + NN;
        hipMemsetAsync(d_ws, 0, flags_bytes, stream);
        k_persist<<<NBLK, TPB, 0, stream>>>(K, z0, zb0, zb1, out,
                                            omega_p, dt_p, flags);
    } else {
        float2* zb0 = (float2*)d_ws;
        float2* zb1 = zb0 + n;
        const float2* cur = z0;
        for (int s = 0; s < NSTEPS; ++s) {
            float2* nxt = (s == NSTEPS - 1) ? out : ((s & 1) ? zb1 : zb0);
            k_step_f32<<<(n + 3) / 4, 256, 0, stream>>>(K, cur, nxt, omega_p, dt_p, n);
            cur = nxt;
        }
    }
}